// Round 5
// baseline (111.413 us; speedup 1.0000x reference)
//
#include <hip/hip_runtime.h>

// Problem constants (fixed by the reference file)
#define BATCH 2048
#define MM    256
#define DD    1024

// Main-kernel tiling: monolithic 128b x 64m x 64d tile, ONE barrier per block.
#define BB 128
#define BM 64
#define DC 64
#define SD (DD / DC)      // 16 d-blocks
#define NBT (BATCH / BB)  // 16 b-blocks
#define XS_TILE (DC * BB) // 8192 floats = 32 KB
#define RS_TILE (DC * BM) // 4096 floats = 16 KB

#define LOG2E 1.4426950408889634f
#define LN2   0.6931471805599453f

typedef float v2f __attribute__((ext_vector_type(2)));

// ---- exact log2 bookkeeping via frexp (full-rate VALU) ----
__device__ __forceinline__ float fr_mant(float x) {
    return __builtin_amdgcn_frexp_mantf(x);
}
__device__ __forceinline__ int fr_exp(float x) {
    return __builtin_amdgcn_frexp_expf(x);
}

// bf16 helpers (RNE)
__device__ __forceinline__ unsigned short f2bf(float f) {
    unsigned u = __float_as_uint(f);
    u += 0x7FFFu + ((u >> 16) & 1u);
    return (unsigned short)(u >> 16);
}
__device__ __forceinline__ float bf2f(unsigned short u) {
    return __uint_as_float((unsigned)u << 16);
}

// async global->LDS, 16 B per lane; lds dest = wave-uniform base + lane*16
__device__ __forceinline__ void gl_lds16(const float* g, float* l) {
    __builtin_amdgcn_global_load_lds(
        (const __attribute__((address_space(1))) unsigned int*)g,
        (__attribute__((address_space(3))) unsigned int*)l, 16, 0, 0);
}

// ---------------------------------------------------------------------------
// Kernel A: r[m][d] = e^z - 1 into rbuf (natural [m][d]);
// cst[m] = sum_d log2 q[m][d] + log2 softmax(W)[m]
// ---------------------------------------------------------------------------
__global__ __launch_bounds__(256) void precomp_kernel(
        const float* __restrict__ P, const float* __restrict__ Wv,
        float* __restrict__ rbuf, float* __restrict__ cst) {
    const int m = blockIdx.x;
    const int t = threadIdx.x;
    const int lane = t & 63, wid = t >> 6;

    float4 z = ((const float4*)(P + (size_t)m * DD))[t];
    float e0 = __expf(z.x), e1 = __expf(z.y), e2 = __expf(z.z), e3 = __expf(z.w);
    ((float4*)(rbuf + (size_t)m * DD))[t] =
        make_float4(e0 - 1.f, e1 - 1.f, e2 - 1.f, e3 - 1.f);
    float part = -(__log2f(1.f + e0) + __log2f(1.f + e1) +
                   __log2f(1.f + e2) + __log2f(1.f + e3));

    __shared__ float smA[4], smB[4];

    #pragma unroll
    for (int o = 32; o; o >>= 1) part += __shfl_xor(part, o);
    if (lane == 0) smA[wid] = part;

    float w = Wv[t];
    float mx = w;
    #pragma unroll
    for (int o = 32; o; o >>= 1) mx = fmaxf(mx, __shfl_xor(mx, o));
    if (lane == 0) smB[wid] = mx;
    __syncthreads();

    float rowc = smA[0] + smA[1] + smA[2] + smA[3];
    float gmx  = fmaxf(fmaxf(smB[0], smB[1]), fmaxf(smB[2], smB[3]));

    float se = __expf(w - gmx);
    #pragma unroll
    for (int o = 32; o; o >>= 1) se += __shfl_xor(se, o);
    __syncthreads();
    if (lane == 0) smA[wid] = se;
    __syncthreads();

    if (t == 0) {
        float sum = smA[0] + smA[1] + smA[2] + smA[3];
        cst[m] = rowc + (Wv[m] - gmx) * LOG2E - __log2f(sum);
    }
}

// ---------------------------------------------------------------------------
// Kernel S: swizzle x -> xs and rbuf -> rs into transposed tile order so that
// global_load_lds's lane-contiguous LDS writes land in the exact fragment
// layout main_kernel reads (no in-kernel transpose, no padding).
//   xs tile(b_id,d_id)[kc][brow] = x[b_id*128+brow][d_id*64+kc]
//   rs tile(m_id,d_id)[kc][mrow] = rbuf[m_id*64+mrow][d_id*64+kc]
// ---------------------------------------------------------------------------
__global__ __launch_bounds__(256) void swz_kernel(
        const float* __restrict__ x, const float* __restrict__ rbuf,
        float* __restrict__ xs, float* __restrict__ rs) {
    __shared__ float t[128 * 65];
    const int tid = threadIdx.x;
    const int bx = blockIdx.x, by = blockIdx.y;

    const float* src;
    float* dst;
    int rows;
    if (bx < NBT) {           // x tile: 128 rows
        rows = BB;
        src = x + (size_t)bx * BB * DD + by * DC;
        dst = xs + ((size_t)bx * SD + by) * XS_TILE;
    } else {                  // r tile: 64 rows
        rows = BM;
        src = rbuf + (size_t)(bx - NBT) * BM * DD + by * DC;
        dst = rs + ((size_t)(bx - NBT) * SD + by) * RS_TILE;
    }

    const int nf4 = rows * (DC / 4);       // float4s per tile
    for (int k = 0; k < nf4 / 256; ++k) {
        int idx4 = tid + 256 * k;
        int row = idx4 >> 4;               // DC/4 = 16 f4 per row
        int c4  = idx4 & 15;
        float4 v = *(const float4*)(src + (size_t)row * DD + c4 * 4);
        t[row * 65 + c4 * 4 + 0] = v.x;
        t[row * 65 + c4 * 4 + 1] = v.y;
        t[row * 65 + c4 * 4 + 2] = v.z;
        t[row * 65 + c4 * 4 + 3] = v.w;
    }
    __syncthreads();
    const int r4 = rows >> 2;
    for (int k = 0; k < nf4 / 256; ++k) {
        int o4 = tid + 256 * k;
        int kc  = o4 / r4;
        int br4 = o4 - kc * r4;
        float4 w;
        w.x = t[(br4 * 4 + 0) * 65 + kc];
        w.y = t[(br4 * 4 + 1) * 65 + kc];
        w.z = t[(br4 * 4 + 2) * 65 + kc];
        w.w = t[(br4 * 4 + 3) * 65 + kc];
        ((float4*)dst)[o4] = w;
    }
}

// ---------------------------------------------------------------------------
// Kernel B: pbuf[d_id][b][m] (bf16) = sum_{d in 64-block} log2(1 + x*r)
// global_load_lds staging, ONE __syncthreads, unbroken 64-kc compute run.
// ---------------------------------------------------------------------------
__global__ __launch_bounds__(256, 3) void main_kernel(
        const float* __restrict__ xs, const float* __restrict__ rs,
        unsigned short* __restrict__ pbuf) {
    __shared__ __align__(16) float lx[XS_TILE];   // [64 kc][128 b]  32 KB
    __shared__ __align__(16) float lr[RS_TILE];   // [64 kc][64 m]   16 KB

    const int tid  = threadIdx.x;
    const int lane = tid & 63;
    const int wv   = tid >> 6;
    const int tx = tid & 15;    // m
    const int ty = tid >> 4;    // b
    const int m_id = blockIdx.x;
    const int b_id = blockIdx.y;
    const int d_id = blockIdx.z;

    const float* xg = xs + ((size_t)b_id * SD + d_id) * XS_TILE;
    const float* rg = rs + ((size_t)m_id * SD + d_id) * RS_TILE;

    // stage: per wave 8 KB of x + 4 KB of r, 1 KB per issue
    #pragma unroll
    for (int k = 0; k < 8; ++k) {
        const int off = (wv * 8 + k) * 256;
        gl_lds16(xg + off + lane * 4, lx + off);
    }
    #pragma unroll
    for (int k = 0; k < 4; ++k) {
        const int off = (wv * 4 + k) * 256;
        gl_lds16(rg + off + lane * 4, lr + off);
    }

    const v2f one2 = {1.0f, 1.0f};
    v2f prod[4][4];
    int acce[8][4];
    #pragma unroll
    for (int i2 = 0; i2 < 4; ++i2)
        #pragma unroll
        for (int j = 0; j < 4; ++j) prod[i2][j] = one2;
    #pragma unroll
    for (int i = 0; i < 8; ++i)
        #pragma unroll
        for (int j = 0; j < 4; ++j) acce[i][j] = 0;

    __syncthreads();   // drains vmcnt -> all tiles resident

    const float4* xa = (const float4*)(lx + 8 * ty);  // +kc*32 (f4), +1
    const float4* rb = (const float4*)(lr + 4 * tx);  // +kc*16 (f4)

    #pragma unroll
    for (int g = 0; g < 8; ++g) {
        #pragma unroll
        for (int s = 0; s < 8; ++s) {
            const int kc = g * 8 + s;
            float4 x0 = xa[kc * 32];
            float4 x1 = xa[kc * 32 + 1];
            float4 rv = rb[kc * 16];
            v2f xp2[4] = {{x0.x, x0.y}, {x0.z, x0.w},
                          {x1.x, x1.y}, {x1.z, x1.w}};
            float rf[4] = {rv.x, rv.y, rv.z, rv.w};
            #pragma unroll
            for (int j = 0; j < 4; ++j) {
                v2f rr = {rf[j], rf[j]};
                #pragma unroll
                for (int i2 = 0; i2 < 4; ++i2) {
                    v2f tt = __builtin_elementwise_fma(xp2[i2], rr, one2);
                    prod[i2][j] = prod[i2][j] * tt;
                }
            }
        }
        // close group of 8 d: exact exponent extraction (range-safe)
        #pragma unroll
        for (int i2 = 0; i2 < 4; ++i2)
            #pragma unroll
            for (int j = 0; j < 4; ++j) {
                v2f p = prod[i2][j];
                acce[2 * i2 + 0][j] += fr_exp(p.x);
                acce[2 * i2 + 1][j] += fr_exp(p.y);
                p.x = fr_mant(p.x);
                p.y = fr_mant(p.y);
                prod[i2][j] = p;
            }
    }

    // epilogue: bf16 partials, coalesced ushort4 stores
    unsigned short* pb = pbuf + ((size_t)d_id * BATCH + (size_t)b_id * BB) * MM
                              + (size_t)m_id * BM;
    #pragma unroll
    for (int i2 = 0; i2 < 4; ++i2)
        #pragma unroll
        for (int h = 0; h < 2; ++h) {
            const int i = 2 * i2 + h;
            float f0 = (float)acce[i][0] + __log2f(h ? prod[i2][0].y : prod[i2][0].x);
            float f1 = (float)acce[i][1] + __log2f(h ? prod[i2][1].y : prod[i2][1].x);
            float f2 = (float)acce[i][2] + __log2f(h ? prod[i2][2].y : prod[i2][2].x);
            float f3 = (float)acce[i][3] + __log2f(h ? prod[i2][3].y : prod[i2][3].x);
            ushort4 w;
            w.x = f2bf(f0); w.y = f2bf(f1); w.z = f2bf(f2); w.w = f2bf(f3);
            *(ushort4*)&pb[(size_t)(8 * ty + i) * MM + 4 * tx] = w;
        }
}

// ---------------------------------------------------------------------------
// Kernel C: sum 16 bf16 partials + cst, per-batch logsumexp over m.
// One wave per batch; lane covers 4 m's.
// ---------------------------------------------------------------------------
__global__ __launch_bounds__(256) void finalize_kernel(
        const unsigned short* __restrict__ pbuf, const float* __restrict__ cst,
        float* __restrict__ out) {
    const int lane = threadIdx.x & 63;
    const int w = threadIdx.x >> 6;
    const int b = blockIdx.x * 4 + w;

    float4 v = ((const float4*)cst)[lane];
    const ushort4* pb = (const ushort4*)pbuf + (size_t)b * (MM / 4) + lane;
    #pragma unroll
    for (int s = 0; s < SD; ++s) {
        ushort4 t = pb[(size_t)s * BATCH * (MM / 4)];
        v.x += bf2f(t.x); v.y += bf2f(t.y); v.z += bf2f(t.z); v.w += bf2f(t.w);
    }

    float mx = fmaxf(fmaxf(v.x, v.y), fmaxf(v.z, v.w));
    #pragma unroll
    for (int o = 32; o; o >>= 1) mx = fmaxf(mx, __shfl_xor(mx, o));

    float s = exp2f(v.x - mx) + exp2f(v.y - mx) + exp2f(v.z - mx) + exp2f(v.w - mx);
    #pragma unroll
    for (int o = 32; o; o >>= 1) s += __shfl_xor(s, o);

    if (lane == 0) out[b] = LN2 * (mx + __log2f(s));
}

extern "C" void kernel_launch(void* const* d_in, const int* in_sizes, int n_in,
                              void* d_out, int out_size, void* d_ws, size_t ws_size,
                              hipStream_t stream) {
    const float* x  = (const float*)d_in[0];
    const float* Wv = (const float*)d_in[1];
    const float* P  = (const float*)d_in[2];

    // ws layout: [xs 8MiB][rs 1MiB][rbuf 1MiB][cst 1KiB][pbuf bf16 16MiB] = 26.3MiB
    // (ws_size >= 33 MiB proven by rounds 1-4's fp32 sd=16 pbuf fitting)
    float* ws   = (float*)d_ws;
    float* xs   = ws;
    float* rs   = xs + (size_t)NBT * SD * XS_TILE;
    float* rbuf = rs + (size_t)(MM / BM) * SD * RS_TILE;
    float* cst  = rbuf + (size_t)MM * DD;
    unsigned short* pbuf = (unsigned short*)(cst + MM);

    precomp_kernel<<<MM, 256, 0, stream>>>(P, Wv, rbuf, cst);
    dim3 gS(NBT + MM / BM, SD);
    swz_kernel<<<gS, 256, 0, stream>>>(x, rbuf, xs, rs);
    dim3 gB(MM / BM, NBT, SD);
    main_kernel<<<gB, 256, 0, stream>>>(xs, rs, pbuf);
    finalize_kernel<<<BATCH / 4, 256, 0, stream>>>(pbuf, cst, (float*)d_out);
}